// Round 5
// baseline (724.622 us; speedup 1.0000x reference)
//
#include <hip/hip_runtime.h>
#include <hip/hip_bf16.h>

typedef __attribute__((ext_vector_type(4))) float          f32x4;
typedef __attribute__((ext_vector_type(8))) short          bf16x8;
typedef __attribute__((ext_vector_type(4))) unsigned short ushort4v;

#define NF_ 256
#define E_  2048
#define T_  4096
#define BM_ 256
#define BN_ 128
#define BK_ 32
#define NKT (E_ / BK_)   // 64 K-steps

__device__ __forceinline__ unsigned short f2bf(float x) {
    __hip_bfloat16 h = __float2bfloat16(x);   // RNE; pairs fuse to v_cvt_pk_bf16_f32
    return __builtin_bit_cast(unsigned short, h);
}

__global__ __launch_bounds__(512, 4)
void mesh_unpool_gemm(const float* __restrict__ features,
                      const float* __restrict__ groups,
                      const float* __restrict__ occur,
                      float* __restrict__ out)
{
    // 512 blocks; xcd = bid&7 (round-robin dispatch), 2 batches per XCD.
    const int bid = blockIdx.x;
    const int xcd = bid & 7;
    const int s   = bid >> 3;             // 0..63
    const int b   = xcd * 2 + (s >> 5);   // batch
    const int n0  = (s & 31) * BN_;       // t-column block

    const float* __restrict__ fA = features + (size_t)b * NF_ * E_;
    const float* __restrict__ fB = groups   + (size_t)b * E_ * T_;
    const float* __restrict__ fO = occur    + (size_t)b * T_;
    float* __restrict__ fC       = out      + (size_t)b * NF_ * T_;

    // bf16 double-buffered tiles, 16B-chunk XOR swizzle. 48 KB total -> 2 blocks/CU.
    __shared__ unsigned short As[2][BM_ * BK_];   // [256][32]  2 x 16 KB
    __shared__ unsigned short Bs[2][BN_ * BK_];   // [128][32]  2 x 8 KB (k-transposed)

    const int tid  = threadIdx.x;
    const int lane = tid & 63;
    const int wave = tid >> 6;            // 0..7
    const int wm   = wave >> 1;           // 0..3 (M quadrant)
    const int wn   = wave & 1;            // 0..1 (N half)
    const int l15  = lane & 15;
    const int kg   = lane >> 4;           // frag k-offset = kg*8
    const int sw   = (l15 >> 2) & 3;
    const int ako  = (kg ^ sw) << 3;      // A frag chunk (shorts); A swizzle: chunk^=(row>>2)&3

    // ---- A staging: thread owns k-chunk ac of rows ar0 + 64j (coalesced). ----
    const int ac  = tid & 7;              // float4 k-chunk
    const int ar0 = tid >> 3;             // 0..63
    const float* aSrc = fA + (size_t)ar0 * E_ + ac * 4;
    const int aWOff = (((ac >> 1) ^ ((ar0 >> 2) & 3)) << 3) + ((ac & 1) << 2); // shorts

    // ---- B staging: thread owns cols tq*4..+3, k rows 2kp,2kp+1 (coalesced). ----
    // Write swizzle: chunk = (kp>>2) ^ ((t>>2)&3) ^ ((t>>4)&3); read absorbs as ^fn.
    const int tq = tid & 31;
    const int kp = tid >> 5;              // 0..15
    const float* bSrc = fB + (size_t)(2 * kp) * T_ + n0 + tq * 4;
    const int bChunk = (((kp >> 2) ^ (tq & 3) ^ ((tq >> 2) & 3)) << 3);
    const int bKo    = (kp & 3) << 1;

    // 3-deep register pipeline, named sets (compile-time indices only).
    f32x4 a0[4], a1[4], a2[4];
    f32x4 b0[2], b1[2], b2[2];

    f32x4 acc[4][4];
    #pragma unroll
    for (int i = 0; i < 4; ++i)
        #pragma unroll
        for (int j = 0; j < 4; ++j)
            acc[i][j] = (f32x4){0.f, 0.f, 0.f, 0.f};

    auto loadA = [&](f32x4 (&ra)[4], int kt) {
        const float* p = aSrc + kt * BK_;
        #pragma unroll
        for (int j = 0; j < 4; ++j)
            ra[j] = *(const f32x4*)(p + (size_t)j * 64 * E_);
    };
    auto loadB = [&](f32x4 (&rb)[2], int kt) {
        const float* p = bSrc + (size_t)kt * BK_ * T_;
        rb[0] = *(const f32x4*)p;
        rb[1] = *(const f32x4*)(p + T_);
    };
    auto storeA = [&](unsigned short* A, f32x4 (&ra)[4]) {
        #pragma unroll
        for (int j = 0; j < 4; ++j) {
            ushort4v pk;
            #pragma unroll
            for (int e = 0; e < 4; ++e) pk[e] = f2bf(ra[j][e]);
            *(ushort4v*)&A[(ar0 + 64 * j) * BK_ + aWOff] = pk;   // ds_write_b64
        }
    };
    auto storeB = [&](unsigned short* B, f32x4 (&rb)[2]) {
        #pragma unroll
        for (int i = 0; i < 4; ++i) {
            unsigned pr = (unsigned)f2bf(rb[0][i]) | ((unsigned)f2bf(rb[1][i]) << 16);
            *(unsigned*)&B[(tq * 4 + i) * BK_ + bChunk + bKo] = pr;
        }
    };
    auto compute = [&](const unsigned short* A, const unsigned short* B) {
        bf16x8 af[4];
        #pragma unroll
        for (int fm = 0; fm < 4; ++fm)
            af[fm] = *(const bf16x8*)&A[(wm * 64 + fm * 16 + l15) * BK_ + ako];
        #pragma unroll
        for (int fn = 0; fn < 4; ++fn) {
            bf16x8 bf = *(const bf16x8*)&B[(wn * 64 + fn * 16 + l15) * BK_ + ((kg ^ sw ^ fn) << 3)];
            #pragma unroll
            for (int fm = 0; fm < 4; ++fm)
                acc[fm][fn] = __builtin_amdgcn_mfma_f32_16x16x32_bf16(
                    af[fm], bf, acc[fm][fn], 0, 0, 0);
        }
    };

    // Step kt: issue tile kt+3 (6 loads), vmcnt(12) [tile kt+1 arrived; kt+2,kt+3
    // = 12 ops stay in flight across the barrier], cvt+store tile kt+1 to LDS,
    // compute tile kt, lgkm(0), barrier. Every tile gets ~2 steps of latency cover.
#define STEP(KT, AL, BL, AS_, BS_, LC, LN, HASLD, VMN)                  \
    {                                                                   \
        if (HASLD) { loadA(AL, (KT) + 3); loadB(BL, (KT) + 3); }        \
        __builtin_amdgcn_sched_barrier(0);                              \
        asm volatile("s_waitcnt vmcnt(" #VMN ")" ::: "memory");         \
        __builtin_amdgcn_sched_barrier(0);                              \
        storeA(As[LN], AS_);                                            \
        storeB(Bs[LN], BS_);                                            \
        compute(As[LC], Bs[LC]);                                        \
        __builtin_amdgcn_sched_barrier(0);                              \
        asm volatile("s_waitcnt lgkmcnt(0)" ::: "memory");              \
        __builtin_amdgcn_s_barrier();                                   \
    }

    // Prologue: issue tiles 0,1,2; wait tile0; stage it; barrier.
    loadA(a0, 0); loadB(b0, 0);
    loadA(a1, 1); loadB(b1, 1);
    loadA(a2, 2); loadB(b2, 2);
    __builtin_amdgcn_sched_barrier(0);
    asm volatile("s_waitcnt vmcnt(12)" ::: "memory");
    __builtin_amdgcn_sched_barrier(0);
    storeA(As[0], a0);
    storeB(Bs[0], b0);
    asm volatile("s_waitcnt lgkmcnt(0)" ::: "memory");
    __builtin_amdgcn_s_barrier();

    // Steady: kt = 0..59, period-6 (LCM of 3 reg-sets and 2 LDS buffers).
    for (int p = 0; p < 10; ++p) {
        const int kt = p * 6;
        STEP(kt + 0, a0, b0, a1, b1, 0, 1, true, 12);
        STEP(kt + 1, a1, b1, a2, b2, 1, 0, true, 12);
        STEP(kt + 2, a2, b2, a0, b0, 0, 1, true, 12);
        STEP(kt + 3, a0, b0, a1, b1, 1, 0, true, 12);
        STEP(kt + 4, a1, b1, a2, b2, 0, 1, true, 12);
        STEP(kt + 5, a2, b2, a0, b0, 1, 0, true, 12);
    }
    // kt=60: last issue (tile 63). kt=61,62: drain-down (vmcnt 6, 0). kt=63: compute only.
    STEP(60, a0, b0, a1, b1, 0, 1, true,  12);
    STEP(61, a1, b1, a2, b2, 1, 0, false, 6);
    STEP(62, a2, b2, a0, b0, 0, 1, false, 0);
    compute(As[1], Bs[1]);
#undef STEP

    // Epilogue: D layout col=lane&15, row=(lane>>4)*4+r; scale by 1/occ[t].
    // Per kg-group each store covers 64 contiguous bytes (>= HBM sector).
    #pragma unroll
    for (int fn = 0; fn < 4; ++fn) {
        const int t = n0 + wn * 64 + fn * 16 + l15;
        const float ro = 1.0f / fO[t];
        #pragma unroll
        for (int fm = 0; fm < 4; ++fm) {
            const int rb = wm * 64 + fm * 16 + kg * 4;
            #pragma unroll
            for (int r = 0; r < 4; ++r)
                fC[(size_t)(rb + r) * T_ + t] = acc[fm][fn][r] * ro;
        }
    }
}

extern "C" void kernel_launch(void* const* d_in, const int* in_sizes, int n_in,
                              void* d_out, int out_size, void* d_ws, size_t ws_size,
                              hipStream_t stream) {
    const float* features = (const float*)d_in[0];   // [16][256][2048] fp32
    const float* groups   = (const float*)d_in[1];   // [16][2048][4096] fp32
    const float* occur    = (const float*)d_in[2];   // [16][4096] fp32
    float* outp           = (float*)d_out;           // [16][256][4096] fp32

    mesh_unpool_gemm<<<dim3(512), dim3(512, 1, 1), 0, stream>>>(features, groups, occur, outp);
}

// Round 6
// 265.614 us; speedup vs baseline: 2.7281x; 2.7281x over previous
//
#include <hip/hip_runtime.h>
#include <hip/hip_bf16.h>

typedef __attribute__((ext_vector_type(4))) float          f32x4;
typedef __attribute__((ext_vector_type(8))) short          bf16x8;
typedef __attribute__((ext_vector_type(4))) unsigned short ushort4v;
typedef __attribute__((ext_vector_type(8))) unsigned short ushort8;

#define NF_ 256
#define E_  2048
#define T_  4096
#define BN_ 64
#define BK_ 32
#define NKT (E_ / BK_)   // 64 K-steps

__device__ __forceinline__ unsigned short f2bf(float x) {
    __hip_bfloat16 h = __float2bfloat16(x);   // RNE; pairs fuse to v_cvt_pk_bf16_f32
    return __builtin_bit_cast(unsigned short, h);
}

__global__ __launch_bounds__(512, 4)
void mesh_unpool_gemm(const float* __restrict__ features,
                      const float* __restrict__ groups,
                      const float* __restrict__ occur,
                      float* __restrict__ out)
{
    // 1024 blocks; xcd = bid&7 (round-robin dispatch), 2 batches per XCD.
    const int bid = blockIdx.x;
    const int xcd = bid & 7;
    const int s   = bid >> 3;             // 0..127
    const int b   = xcd * 2 + (s >> 6);   // batch
    const int n0  = (s & 63) * BN_;       // t-column block

    const float* __restrict__ fA = features + (size_t)b * NF_ * E_;
    const float* __restrict__ fB = groups   + (size_t)b * E_ * T_;
    const float* __restrict__ fO = occur    + (size_t)b * T_;
    float* __restrict__ fC       = out      + (size_t)b * NF_ * T_;

    // B tile only in LDS. Layout: shorts idx = (k>>3)*512 + col*8 + (k&7).
    // Fragment read = b128 at [kg*512 + col*8]: byte pos (col&7)*16 -> uniform
    // over all 32 banks -> conflict-free. 2 x 4 KB.
    __shared__ unsigned short Bs[2][BN_ * BK_];

    const int tid  = threadIdx.x;
    const int lane = tid & 63;
    const int wave = tid >> 6;            // 0..7; owns output rows wave*32..+31
    const int l15  = lane & 15;
    const int kg   = lane >> 4;           // frag k-offset = kg*8

    // A: wave-private rows, global->reg. Frag fm: row = wave*32 + fm*16 + l15,
    // k = kt*32 + kg*8 .. +7 (two f32x4 loads per frag).
    const float* aP0 = fA + (size_t)(wave * 32 + l15) * E_ + kg * 8;
    const float* aP1 = aP0 + (size_t)16 * E_;

    // B staging: thread covers k = wave*4+j (j=0..3), col = lane. Global row
    // k has 64 lanes x 4B contiguous (coalesced). One b64 LDS write per tile.
    const float* bP    = fB + (size_t)(wave * 4) * T_ + n0 + lane;
    const int    bWidx = (wave >> 1) * 512 + lane * 8 + (wave & 1) * 4;

    // Depth-2 named register sets (all indices compile-time).
    f32x4 aE[4], aO[4];
    float bE[4], bO[4];

    f32x4 acc[2][4];
    #pragma unroll
    for (int i = 0; i < 2; ++i)
        #pragma unroll
        for (int j = 0; j < 4; ++j)
            acc[i][j] = (f32x4){0.f, 0.f, 0.f, 0.f};

    auto issueA = [&](f32x4 (&a)[4], int kt) {
        const float* p0 = aP0 + kt * BK_;
        const float* p1 = aP1 + kt * BK_;
        a[0] = *(const f32x4*)p0;
        a[1] = *(const f32x4*)(p0 + 4);
        a[2] = *(const f32x4*)p1;
        a[3] = *(const f32x4*)(p1 + 4);
    };
    auto issueB = [&](float (&bb)[4], int kt) {
        const float* p = bP + (size_t)kt * BK_ * T_;
        #pragma unroll
        for (int j = 0; j < 4; ++j)
            bb[j] = p[(size_t)j * T_];
    };
    auto storeB = [&](unsigned short* B, float (&bb)[4]) {
        ushort4v pk;
        #pragma unroll
        for (int j = 0; j < 4; ++j) pk[j] = f2bf(bb[j]);
        *(ushort4v*)&B[bWidx] = pk;                      // ds_write_b64
    };
    auto cvtA = [&](const f32x4 (&a)[4], bf16x8& af0, bf16x8& af1) {
        ushort8 u0, u1;
        #pragma unroll
        for (int e = 0; e < 4; ++e) {
            u0[e] = f2bf(a[0][e]); u0[4 + e] = f2bf(a[1][e]);
            u1[e] = f2bf(a[2][e]); u1[4 + e] = f2bf(a[3][e]);
        }
        af0 = __builtin_bit_cast(bf16x8, u0);
        af1 = __builtin_bit_cast(bf16x8, u1);
    };
    auto computeS = [&](const unsigned short* B, bf16x8 af0, bf16x8 af1) {
        bf16x8 bfr[4];
        #pragma unroll
        for (int fn = 0; fn < 4; ++fn)
            bfr[fn] = *(const bf16x8*)&B[kg * 512 + (fn * 16 + l15) * 8];
        #pragma unroll
        for (int fn = 0; fn < 4; ++fn) {
            acc[0][fn] = __builtin_amdgcn_mfma_f32_16x16x32_bf16(af0, bfr[fn], acc[0][fn], 0, 0, 0);
            acc[1][fn] = __builtin_amdgcn_mfma_f32_16x16x32_bf16(af1, bfr[fn], acc[1][fn], 0, 0, 0);
        }
    };

    // Step kt: cvt A(kt) [frees reg set], issue tile kt+2 into freed sets (8 VMEM),
    // vmcnt(8) [tile kt+1 arrived, kt+2 stays in flight across barrier],
    // store B(kt+1) to LDS, MFMA on tile kt, lgkm drain, raw barrier.
#define STEP(AREG, BREGSTORE, AISS, BISS, BUFC, BUFN, KT)               \
    {                                                                   \
        bf16x8 af0, af1;                                                \
        cvtA(AREG, af0, af1);                                           \
        __builtin_amdgcn_sched_barrier(0);                              \
        issueA(AISS, (KT) + 2);                                         \
        issueB(BISS, (KT) + 2);                                         \
        __builtin_amdgcn_sched_barrier(0);                              \
        asm volatile("s_waitcnt vmcnt(8)" ::: "memory");                \
        __builtin_amdgcn_sched_barrier(0);                              \
        storeB(Bs[BUFN], BREGSTORE);                                    \
        computeS(Bs[BUFC], af0, af1);                                   \
        __builtin_amdgcn_sched_barrier(0);                              \
        asm volatile("s_waitcnt lgkmcnt(0)" ::: "memory");              \
        __builtin_amdgcn_s_barrier();                                   \
    }

    // Prologue: issue tiles 0 (E-sets) and 1 (O-sets); wait tile 0; stage B(0).
    issueA(aE, 0); issueB(bE, 0);
    issueA(aO, 1); issueB(bO, 1);
    __builtin_amdgcn_sched_barrier(0);
    asm volatile("s_waitcnt vmcnt(8)" ::: "memory");    // tile 0 arrived
    __builtin_amdgcn_sched_barrier(0);
    storeB(Bs[0], bE);
    asm volatile("s_waitcnt lgkmcnt(0)" ::: "memory");
    __builtin_amdgcn_s_barrier();

    // Steady: kt = 0..61 (unrolled x2; even step uses E sets / buf0).
    for (int p = 0; p < 31; ++p) {
        const int kt = 2 * p;
        STEP(aE, bO, aE, bE, 0, 1, kt);       // compute tile kt, store B(kt+1), issue kt+2
        STEP(aO, bE, aO, bO, 1, 0, kt + 1);
    }
    // kt = 62: no more issues; drain tile 63; store B(63); compute 62.
    {
        bf16x8 af0, af1;
        cvtA(aE, af0, af1);
        __builtin_amdgcn_sched_barrier(0);
        asm volatile("s_waitcnt vmcnt(0)" ::: "memory");   // tile 63 arrived
        __builtin_amdgcn_sched_barrier(0);
        storeB(Bs[1], bO);
        computeS(Bs[0], af0, af1);
        __builtin_amdgcn_sched_barrier(0);
        asm volatile("s_waitcnt lgkmcnt(0)" ::: "memory");
        __builtin_amdgcn_s_barrier();
    }
    // kt = 63: pure compute.
    {
        bf16x8 af0, af1;
        cvtA(aO, af0, af1);
        computeS(Bs[1], af0, af1);
    }
#undef STEP

    // Epilogue: D layout col=lane&15, row=(lane>>4)*4+r; scale by 1/occ[t].
    #pragma unroll
    for (int fn = 0; fn < 4; ++fn) {
        const int t  = n0 + fn * 16 + l15;
        const float ro = 1.0f / fO[t];
        #pragma unroll
        for (int fm = 0; fm < 2; ++fm) {
            const int rb = wave * 32 + fm * 16 + kg * 4;
            #pragma unroll
            for (int r = 0; r < 4; ++r)
                fC[(size_t)(rb + r) * T_ + t] = acc[fm][fn][r] * ro;
        }
    }
}

extern "C" void kernel_launch(void* const* d_in, const int* in_sizes, int n_in,
                              void* d_out, int out_size, void* d_ws, size_t ws_size,
                              hipStream_t stream) {
    const float* features = (const float*)d_in[0];   // [16][256][2048] fp32
    const float* groups   = (const float*)d_in[1];   // [16][2048][4096] fp32
    const float* occur    = (const float*)d_in[2];   // [16][4096] fp32
    float* outp           = (float*)d_out;           // [16][256][4096] fp32

    mesh_unpool_gemm<<<dim3(1024), dim3(512, 1, 1), 0, stream>>>(features, groups, occur, outp);
}

// Round 7
// 128.432 us; speedup vs baseline: 5.6421x; 2.0681x over previous
//
#include <hip/hip_runtime.h>
#include <hip/hip_bf16.h>

typedef __attribute__((ext_vector_type(4))) float          f32x4;
typedef __attribute__((ext_vector_type(8))) short          bf16x8;
typedef __attribute__((ext_vector_type(4))) unsigned short ushort4v;
typedef __attribute__((ext_vector_type(8))) unsigned short ushort8;

#define NF_ 256
#define E_  2048
#define T_  4096
#define BK_ 32
#define TILE_SH 8192          // shorts per 256x32 bf16 tile (16 KB)
#define NKT (E_ / BK_)        // 64 K-steps

__device__ __forceinline__ unsigned short f2bf(float x) {
    __hip_bfloat16 h = __float2bfloat16(x);   // RNE; pairs fuse to v_cvt_pk_bf16_f32
    return __builtin_bit_cast(unsigned short, h);
}

__global__ __launch_bounds__(512, 2)
void mesh_unpool_gemm(const float* __restrict__ features,
                      const float* __restrict__ groups,
                      const float* __restrict__ occur,
                      float* __restrict__ out)
{
    extern __shared__ unsigned short smem[];
    unsigned short* As0 = smem;              // 4 x 16 KB = 64 KB
    unsigned short* As1 = As0 + TILE_SH;
    unsigned short* Bs0 = As1 + TILE_SH;
    unsigned short* Bs1 = Bs0 + TILE_SH;

    // 256 blocks (1/CU). xcd = bid&7 (round-robin dispatch); 2 batches per XCD
    // -> 4 MB of features per XCD L2.
    const int bid = blockIdx.x;
    const int xcd = bid & 7;
    const int s   = bid >> 3;             // 0..31
    const int b   = xcd * 2 + (s >> 4);   // batch
    const int n0  = (s & 15) * 256;       // t-column block

    const float* __restrict__ fA = features + (size_t)b * NF_ * E_;
    const float* __restrict__ fB = groups   + (size_t)b * E_ * T_;
    const float* __restrict__ fO = occur    + (size_t)b * T_;
    float* __restrict__ fC       = out      + (size_t)b * NF_ * T_;

    const int tid  = threadIdx.x;
    const int lane = tid & 63;
    const int wave = tid >> 6;            // 0..7
    const int wm   = wave >> 2;           // 0..1 (M half, 128 rows)
    const int wn   = wave & 3;            // 0..3 (N quadrant, 64 cols)
    const int l15  = lane & 15;
    const int kg   = lane >> 4;           // k-octet, frag k-offset = kg*8

    // LDS tile layout (shorts): idx = (k>>3)*2048 + row*8 + (k&7).
    // Frag read = b128 at [kg*2048 + row*8]: 16 rows x 4 kg -> 8 lanes per
    // bank-group = the 1KB/wave minimum (conflict-free). Same for writes.

    // ---- A staging: thread owns row ar, k-half ah (16 consecutive floats). ----
    const int ar = tid >> 1;              // 0..255
    const int ah = tid & 1;
    const float* aSrc = fA + (size_t)ar * E_ + ah * 16;
    const int aW = (2 * ah) * 2048 + ar * 8;     // + 2048 for second octet

    // ---- B staging: thread owns cols tq*4..+3 x k-quad kp*4..+3 (4x4 block). ----
    const int tq = tid & 63;
    const int kp = tid >> 6;              // 0..7
    const float* bSrc = fB + (size_t)(kp * 4) * T_ + n0 + tq * 4;
    const int bW = (kp >> 1) * 2048 + ((kp & 1) << 2);   // + c*8 per col

    f32x4 aR[4];                          // A depth-1 staging regs
    f32x4 bE[4], bO[4];                   // B depth-2 named sets

    f32x4 acc[8][4];
    #pragma unroll
    for (int i = 0; i < 8; ++i)
        #pragma unroll
        for (int j = 0; j < 4; ++j)
            acc[i][j] = (f32x4){0.f, 0.f, 0.f, 0.f};

    auto loadA = [&](int kt) {
        const float* p = aSrc + kt * BK_;
        #pragma unroll
        for (int j = 0; j < 4; ++j)
            aR[j] = *(const f32x4*)(p + 4 * j);
    };
    auto loadB = [&](f32x4 (&br)[4], int kt) {
        const float* p = bSrc + (size_t)kt * BK_ * T_;
        #pragma unroll
        for (int i = 0; i < 4; ++i)
            br[i] = *(const f32x4*)(p + (size_t)i * T_);
    };
    auto storeA = [&](unsigned short* A) {
        ushort8 u0, u1;
        #pragma unroll
        for (int e = 0; e < 4; ++e) {
            u0[e] = f2bf(aR[0][e]); u0[4 + e] = f2bf(aR[1][e]);
            u1[e] = f2bf(aR[2][e]); u1[4 + e] = f2bf(aR[3][e]);
        }
        *(ushort8*)&A[aW]        = u0;    // ds_write_b128
        *(ushort8*)&A[aW + 2048] = u1;
    };
    auto storeB = [&](unsigned short* B, f32x4 (&br)[4]) {
        #pragma unroll
        for (int j = 0; j < 4; ++j) {     // 4x4 register transpose
            ushort4v v;
            #pragma unroll
            for (int i = 0; i < 4; ++i) v[i] = f2bf(br[i][j]);
            *(ushort4v*)&B[bW + (tq * 4 + j) * 8] = v;   // ds_write_b64
        }
    };
    auto compute = [&](const unsigned short* A, const unsigned short* B) {
        bf16x8 bfr[4];
        #pragma unroll
        for (int fn = 0; fn < 4; ++fn)
            bfr[fn] = *(const bf16x8*)&B[kg * 2048 + (wn * 64 + fn * 16 + l15) * 8];
        #pragma unroll
        for (int fm = 0; fm < 8; ++fm) {
            bf16x8 af = *(const bf16x8*)&A[kg * 2048 + (wm * 128 + fm * 16 + l15) * 8];
            #pragma unroll
            for (int fn = 0; fn < 4; ++fn)
                acc[fm][fn] = __builtin_amdgcn_mfma_f32_16x16x32_bf16(
                    af, bfr[fn], acc[fm][fn], 0, 0, 0);
        }
    };

    // Step kt: issue A(kt+1)[4] + B(kt+2)[4]; compute(kt); vmcnt(4) [A(kt+1) and
    // B(kt+1) arrived, B(kt+2) stays in flight across the barrier]; cvt+store
    // tile kt+1; lgkm drain; raw barrier. B gets ~2 steps of latency cover.
#define STEP(KT, AC, BC, AN, BN2, BISS, BST, VMN)                       \
    {                                                                   \
        loadA((KT) + 1);                                                \
        if ((KT) + 2 < NKT) loadB(BISS, (KT) + 2);                      \
        __builtin_amdgcn_sched_barrier(0);                              \
        compute(AC, BC);                                                \
        __builtin_amdgcn_sched_barrier(0);                              \
        asm volatile("s_waitcnt vmcnt(" #VMN ")" ::: "memory");         \
        storeA(AN);                                                     \
        storeB(BN2, BST);                                               \
        __builtin_amdgcn_sched_barrier(0);                              \
        asm volatile("s_waitcnt lgkmcnt(0)" ::: "memory");              \
        __builtin_amdgcn_s_barrier();                                   \
    }

    // Prologue: issue A(0), B(0)->bE, B(1)->bO; vmcnt(4); stage tile 0; barrier.
    loadA(0);
    loadB(bE, 0);
    loadB(bO, 1);
    __builtin_amdgcn_sched_barrier(0);
    asm volatile("s_waitcnt vmcnt(4)" ::: "memory");   // A(0)+B(0) done; B(1) in flight
    storeA(As0);
    storeB(Bs0, bE);
    __builtin_amdgcn_sched_barrier(0);
    asm volatile("s_waitcnt lgkmcnt(0)" ::: "memory");
    __builtin_amdgcn_s_barrier();

    // Steady: kt = 0..61 (unrolled x2 for static bE/bO alternation).
    for (int p = 0; p < 31; ++p) {
        STEP(2 * p,     As0, Bs0, As1, Bs1, bE, bO, 4);
        STEP(2 * p + 1, As1, Bs1, As0, Bs0, bO, bE, 4);
    }
    // kt = 62: nothing new to issue beyond A(63); full drain before last stage.
    STEP(62, As0, Bs0, As1, Bs1, bE, bO, 0);
    // kt = 63: pure compute.
    compute(As1, Bs1);
#undef STEP

    // Epilogue: D layout col=lane&15, row=(lane>>4)*4+r; scale by 1/occ[t].
    #pragma unroll
    for (int fn = 0; fn < 4; ++fn) {
        const int t  = n0 + wn * 64 + fn * 16 + l15;
        const float ro = 1.0f / fO[t];
        #pragma unroll
        for (int fm = 0; fm < 8; ++fm) {
            const int rb = wm * 128 + fm * 16 + kg * 4;
            #pragma unroll
            for (int r = 0; r < 4; ++r)
                fC[(size_t)(rb + r) * T_ + t] = acc[fm][fn][r] * ro;
        }
    }
}

extern "C" void kernel_launch(void* const* d_in, const int* in_sizes, int n_in,
                              void* d_out, int out_size, void* d_ws, size_t ws_size,
                              hipStream_t stream) {
    const float* features = (const float*)d_in[0];   // [16][256][2048] fp32
    const float* groups   = (const float*)d_in[1];   // [16][2048][4096] fp32
    const float* occur    = (const float*)d_in[2];   // [16][4096] fp32
    float* outp           = (float*)d_out;           // [16][256][4096] fp32

    // 64 KB dynamic LDS (above the 48 KB default) — host-side, capture-safe.
    hipFuncSetAttribute((const void*)mesh_unpool_gemm,
                        hipFuncAttributeMaxDynamicSharedMemorySize, 65536);
    mesh_unpool_gemm<<<dim3(256), dim3(512, 1, 1), 65536, stream>>>(
        features, groups, occur, outp);
}

// Round 8
// 116.160 us; speedup vs baseline: 6.2381x; 1.1056x over previous
//
#include <hip/hip_runtime.h>
#include <hip/hip_bf16.h>

typedef __attribute__((ext_vector_type(4))) float          f32x4;
typedef __attribute__((ext_vector_type(8))) short          bf16x8;
typedef __attribute__((ext_vector_type(4))) unsigned short ushort4v;
typedef __attribute__((ext_vector_type(8))) unsigned short ushort8;

#define NF_ 256
#define E_  2048
#define T_  4096
#define BK_ 32
#define TILE_SH 8192          // shorts per 256x32 bf16 tile (16 KB)
#define NKT (E_ / BK_)        // 64 K-steps

__device__ __forceinline__ unsigned short f2bf(float x) {
    __hip_bfloat16 h = __float2bfloat16(x);   // RNE; pairs fuse to v_cvt_pk_bf16_f32
    return __builtin_bit_cast(unsigned short, h);
}

__global__ __launch_bounds__(512, 2)
void mesh_unpool_gemm(const float* __restrict__ features,
                      const float* __restrict__ groups,
                      const float* __restrict__ occur,
                      float* __restrict__ out)
{
    extern __shared__ unsigned short smem[];
    unsigned short* As0 = smem;              // 4 x 16 KB = 64 KB
    unsigned short* As1 = As0 + TILE_SH;
    unsigned short* Bs0 = As1 + TILE_SH;
    unsigned short* Bs1 = Bs0 + TILE_SH;

    // 256 blocks (1/CU). xcd = bid&7 (round-robin dispatch); 2 batches per XCD.
    const int bid = blockIdx.x;
    const int xcd = bid & 7;
    const int s   = bid >> 3;             // 0..31
    const int b   = xcd * 2 + (s >> 4);   // batch
    const int n0  = (s & 15) * 256;       // t-column block

    const float* __restrict__ fA = features + (size_t)b * NF_ * E_;
    const float* __restrict__ fB = groups   + (size_t)b * E_ * T_;
    const float* __restrict__ fO = occur    + (size_t)b * T_;
    float* __restrict__ fC       = out      + (size_t)b * NF_ * T_;

    const int tid  = threadIdx.x;
    const int lane = tid & 63;
    const int wave = tid >> 6;            // 0..7
    const int wm   = wave >> 2;           // 0..1 (M half, 128 rows)
    const int wn   = wave & 3;            // 0..3 (N quadrant, 64 cols)
    const int l15  = lane & 15;
    const int kg   = lane >> 4;           // k-octet, frag k-offset = kg*8

    // LDS tile layout (shorts): idx = (k>>3)*2048 + row*8 + (k&7).
    // b128 frag reads/writes: 8 lanes per bank-group = conflict-free minimum.

    // ---- A staging: thread owns row ar, k-half ah (16 consecutive floats). ----
    const int ar = tid >> 1;              // 0..255
    const int ah = tid & 1;
    const float* aSrc = fA + (size_t)ar * E_ + ah * 16;
    const int aW = (2 * ah) * 2048 + ar * 8;     // + 2048 for second octet

    // ---- B staging: thread owns cols tq*4..+3 x k-quad kp*4..+3 (4x4 block). ----
    const int tq = tid & 63;
    const int kp = tid >> 6;              // 0..7
    const float* bSrc = fB + (size_t)(kp * 4) * T_ + n0 + tq * 4;
    const int bW = (kp >> 1) * 2048 + ((kp & 1) << 2);   // + c*8 per col

    f32x4 aR[4];                          // A depth-1 staging regs
    f32x4 bE[4], bO[4];                   // B depth-2 named sets

    f32x4 acc[8][4];
    #pragma unroll
    for (int i = 0; i < 8; ++i)
        #pragma unroll
        for (int j = 0; j < 4; ++j)
            acc[i][j] = (f32x4){0.f, 0.f, 0.f, 0.f};

    auto loadA = [&](int kt) {
        const float* p = aSrc + kt * BK_;
        #pragma unroll
        for (int j = 0; j < 4; ++j)
            aR[j] = *(const f32x4*)(p + 4 * j);
    };
    auto loadB = [&](f32x4 (&br)[4], int kt) {
        // groups stream is read exactly once -> non-temporal (protect L2 for A).
        const float* p = bSrc + (size_t)kt * BK_ * T_;
        #pragma unroll
        for (int i = 0; i < 4; ++i)
            br[i] = __builtin_nontemporal_load((const f32x4*)(p + (size_t)i * T_));
    };
    auto storeA = [&](unsigned short* A) {
        ushort8 u0, u1;
        #pragma unroll
        for (int e = 0; e < 4; ++e) {
            u0[e] = f2bf(aR[0][e]); u0[4 + e] = f2bf(aR[1][e]);
            u1[e] = f2bf(aR[2][e]); u1[4 + e] = f2bf(aR[3][e]);
        }
        *(ushort8*)&A[aW]        = u0;    // ds_write_b128
        *(ushort8*)&A[aW + 2048] = u1;
    };
    auto storeB = [&](unsigned short* B, f32x4 (&br)[4]) {
        #pragma unroll
        for (int j = 0; j < 4; ++j) {     // 4x4 register transpose
            ushort4v v;
            #pragma unroll
            for (int i = 0; i < 4; ++i) v[i] = f2bf(br[i][j]);
            *(ushort4v*)&B[bW + (tq * 4 + j) * 8] = v;   // ds_write_b64
        }
    };
    // Split compute: half0 loads B frags + does fm 0..3; half1 does fm 4..7.
    auto computeH0 = [&](const unsigned short* A, const unsigned short* B,
                         bf16x8 (&bfr)[4]) {
        #pragma unroll
        for (int fn = 0; fn < 4; ++fn)
            bfr[fn] = *(const bf16x8*)&B[kg * 2048 + (wn * 64 + fn * 16 + l15) * 8];
        #pragma unroll
        for (int fm = 0; fm < 4; ++fm) {
            bf16x8 af = *(const bf16x8*)&A[kg * 2048 + (wm * 128 + fm * 16 + l15) * 8];
            #pragma unroll
            for (int fn = 0; fn < 4; ++fn)
                acc[fm][fn] = __builtin_amdgcn_mfma_f32_16x16x32_bf16(
                    af, bfr[fn], acc[fm][fn], 0, 0, 0);
        }
    };
    auto computeH1 = [&](const unsigned short* A, bf16x8 (&bfr)[4]) {
        #pragma unroll
        for (int fm = 4; fm < 8; ++fm) {
            bf16x8 af = *(const bf16x8*)&A[kg * 2048 + (wm * 128 + fm * 16 + l15) * 8];
            #pragma unroll
            for (int fn = 0; fn < 4; ++fn)
                acc[fm][fn] = __builtin_amdgcn_mfma_f32_16x16x32_bf16(
                    af, bfr[fn], acc[fm][fn], 0, 0, 0);
        }
    };

    // Step kt: issue A(kt+1)+B(kt+2); MFMA half0; vmcnt(4) [tile kt+1 arrived,
    // B(kt+2) in flight across barrier]; cvt+store tile kt+1 (other buffer);
    // MFMA half1 (overlaps LDS-write latency); lgkm drain; raw barrier.
#define STEP(KT, AC, BC, AN, BN2, BISS, BST, VMN)                       \
    {                                                                   \
        loadA((KT) + 1);                                                \
        if ((KT) + 2 < NKT) loadB(BISS, (KT) + 2);                      \
        __builtin_amdgcn_sched_barrier(0);                              \
        bf16x8 bfr[4];                                                  \
        computeH0(AC, BC, bfr);                                         \
        __builtin_amdgcn_sched_barrier(0);                              \
        asm volatile("s_waitcnt vmcnt(" #VMN ")" ::: "memory");         \
        storeA(AN);                                                     \
        storeB(BN2, BST);                                               \
        computeH1(AC, bfr);                                             \
        __builtin_amdgcn_sched_barrier(0);                              \
        asm volatile("s_waitcnt lgkmcnt(0)" ::: "memory");              \
        __builtin_amdgcn_s_barrier();                                   \
    }

    // Prologue: issue A(0), B(0)->bE, B(1)->bO; vmcnt(4); stage tile 0; barrier.
    loadA(0);
    loadB(bE, 0);
    loadB(bO, 1);
    __builtin_amdgcn_sched_barrier(0);
    asm volatile("s_waitcnt vmcnt(4)" ::: "memory");   // A(0)+B(0) done; B(1) in flight
    storeA(As0);
    storeB(Bs0, bE);
    __builtin_amdgcn_sched_barrier(0);
    asm volatile("s_waitcnt lgkmcnt(0)" ::: "memory");
    __builtin_amdgcn_s_barrier();

    // Steady: kt = 0..61 (unrolled x2 for static bE/bO alternation).
    for (int p = 0; p < 31; ++p) {
        STEP(2 * p,     As0, Bs0, As1, Bs1, bE, bO, 4);
        STEP(2 * p + 1, As1, Bs1, As0, Bs0, bO, bE, 4);
    }
    // kt = 62: last A issue; full drain before final stage.
    STEP(62, As0, Bs0, As1, Bs1, bE, bO, 0);
    // kt = 63: pure compute.
    {
        bf16x8 bfr[4];
        computeH0(As1, Bs1, bfr);
        computeH1(As1, bfr);
    }
#undef STEP

    // Epilogue: D layout col=lane&15, row=(lane>>4)*4+r; scale by 1/occ[t].
    // Non-temporal stores: C is never re-read.
    #pragma unroll
    for (int fn = 0; fn < 4; ++fn) {
        const int t  = n0 + wn * 64 + fn * 16 + l15;
        const float ro = 1.0f / fO[t];
        #pragma unroll
        for (int fm = 0; fm < 8; ++fm) {
            const int rb = wm * 128 + fm * 16 + kg * 4;
            #pragma unroll
            for (int r = 0; r < 4; ++r)
                __builtin_nontemporal_store(acc[fm][fn][r] * ro,
                                            &fC[(size_t)(rb + r) * T_ + t]);
        }
    }
}

extern "C" void kernel_launch(void* const* d_in, const int* in_sizes, int n_in,
                              void* d_out, int out_size, void* d_ws, size_t ws_size,
                              hipStream_t stream) {
    const float* features = (const float*)d_in[0];   // [16][256][2048] fp32
    const float* groups   = (const float*)d_in[1];   // [16][2048][4096] fp32
    const float* occur    = (const float*)d_in[2];   // [16][4096] fp32
    float* outp           = (float*)d_out;           // [16][256][4096] fp32

    // 64 KB dynamic LDS (above the 48 KB default) — host-side, capture-safe.
    hipFuncSetAttribute((const void*)mesh_unpool_gemm,
                        hipFuncAttributeMaxDynamicSharedMemorySize, 65536);
    mesh_unpool_gemm<<<dim3(256), dim3(512, 1, 1), 65536, stream>>>(
        features, groups, occur, outp);
}